// Round 14
// baseline (12029.498 us; speedup 1.0000x reference)
//
#include <hip/hip_runtime.h>
#include <cstdint>
#include <cstddef>

#define TCHUNK 64
#define NCHUNK 16
#define BATCH 32
#define IDIM 128
#define HDIM 512
#define GDIM 2048
#define ODIM 10
#define XPSTEP (GDIM * BATCH)
#define SLAB_F 16384            // floats per t-slab: 8 groups x 4 chains x 512
#define SLAB_B (SLAB_F * 4)

typedef float f4 __attribute__((ext_vector_type(4)));
typedef float f2 __attribute__((ext_vector_type(2)));

__device__ __forceinline__ void llc_store(float* p, float v) {
  asm volatile("global_store_dword %0, %1, off sc0 sc1" :: "v"(p), "v"(v) : "memory");
}
__device__ __forceinline__ float quad_sum(float x) {
  int t = __builtin_amdgcn_update_dpp(0, __float_as_int(x), 0xB1, 0xF, 0xF, true);
  x += __int_as_float(t);
  t = __builtin_amdgcn_update_dpp(0, __float_as_int(x), 0x4E, 0xF, 0xF, true);
  x += __int_as_float(t);
  return x;
}

#define BARRIER() do {                                                      \
    asm volatile("s_waitcnt lgkmcnt(0)" ::: "memory");                      \
    __builtin_amdgcn_sched_barrier(0);                                      \
    __builtin_amdgcn_s_barrier();                                           \
    __builtin_amdgcn_sched_barrier(0);                                      \
  } while (0)

// ---------------------------------------------------------------------------
// proj: P[tt][n][b] = sum_k X[tt*32+b][k] * W[n][k] + bias[n]
// ---------------------------------------------------------------------------
template<int K>
__launch_bounds__(256, 2)
__global__ void proj_kernel(const float* __restrict__ X,
                            const float* __restrict__ W,
                            const float* __restrict__ bias,
                            float* __restrict__ P) {
  __shared__ float Xs[8][132];
  __shared__ float Ws[8][132];
  const int tid = threadIdx.x;
  const int n0 = blockIdx.x * 128;
  const int m0 = blockIdx.y * 128;
  const int tx = tid & 15, ty = tid >> 4;
  const int lm = tid >> 1;
  const int kq = (tid & 1) * 4;
  f2 acc2[8][4];
#pragma unroll
  for (int i = 0; i < 8; ++i)
#pragma unroll
    for (int j = 0; j < 4; ++j) acc2[i][j] = (f2){0.f, 0.f};

  for (int k0 = 0; k0 < K; k0 += 8) {
    const float4 xv = *(const float4*)&X[(size_t)(m0 + lm) * K + k0 + kq];
    const float4 wv = *(const float4*)&W[(size_t)(n0 + lm) * K + k0 + kq];
    __syncthreads();
    Xs[kq + 0][lm] = xv.x; Xs[kq + 1][lm] = xv.y; Xs[kq + 2][lm] = xv.z; Xs[kq + 3][lm] = xv.w;
    Ws[kq + 0][lm] = wv.x; Ws[kq + 1][lm] = wv.y; Ws[kq + 2][lm] = wv.z; Ws[kq + 3][lm] = wv.w;
    __syncthreads();
#pragma unroll
    for (int kk = 0; kk < 8; ++kk) {
      float a[8];
      *(float4*)&a[0] = *(const float4*)&Xs[kk][ty * 8];
      *(float4*)&a[4] = *(const float4*)&Xs[kk][ty * 8 + 4];
      f2 b2[4];
#pragma unroll
      for (int jp = 0; jp < 4; ++jp) b2[jp] = *(const f2*)&Ws[kk][tx * 8 + 2 * jp];
#pragma unroll
      for (int i = 0; i < 8; ++i)
#pragma unroll
        for (int jp = 0; jp < 4; ++jp) acc2[i][jp] += b2[jp] * a[i];
    }
  }
  const int mb = m0 + ty * 8;
  const int t  = mb >> 5;
  const int b0 = mb & 31;
#pragma unroll
  for (int j = 0; j < 8; ++j) {
    const int n = n0 + tx * 8 + j;
    const float bj = bias[n];
    float* dst = &P[((size_t)t * GDIM + n) * BATCH + b0];
#pragma unroll
    for (int i = 0; i < 8; ++i)
      dst[i] = ((j & 1) ? acc2[i][j >> 1].y : acc2[i][j >> 1].x) + bj;
  }
}

// ---------------------------------------------------------------------------
// scan_dual: TWO verbatim R10 engines per CU. 512 blocks, 2/CU (13.6KB LDS).
// Blocks 0..255 run layer 1 (chunk s), 256..511 run layer 2 (chunk s-1).
// Per-block geometry, VGPR budget (156), LDS layout, staging swizzle,
// barriers — all identical to the verified R10 scan_kernel. The two layers
// are fully uncoupled (own W, slabs, sentinels, polls); the CU scheduler
// fills one layer's poll/barrier stalls with the other layer's waves.
// ---------------------------------------------------------------------------
__launch_bounds__(256, 2)
__global__ void scan_dual(const float* __restrict__ xp1, const float* __restrict__ Whh1,
                          float* __restrict__ hout1, float* __restrict__ hb1,
                          float* __restrict__ ccur1, int first1, int act1,
                          const float* __restrict__ xp2, const float* __restrict__ Whh2,
                          float* __restrict__ hout2, float* __restrict__ hb2,
                          float* __restrict__ ccur2, int first2, int act2) {
  __shared__ float h_s[2112];       // 16 slices x 132 floats (4-float pad/slice)
  __shared__ float red[1024];
  __shared__ float gate_s[256];

  const int bid = blockIdx.x;
  const int lay = bid >> 8;
  if (!(lay ? act2 : act1)) return;
  const float* xp  = lay ? xp2  : xp1;
  const float* Whh = lay ? Whh2 : Whh1;
  float* hout = lay ? hout2 : hout1;
  float* hb   = lay ? hb2   : hb1;
  float* ccur = lay ? ccur2 : ccur1;
  const int first = lay ? first2 : first1;

  const int tid = threadIdx.x;
  const int bidl = bid & 255;
  const int g = bidl & 7, rank = bidl >> 3, slot16 = rank * 16;
  const int w = tid >> 6, l = tid & 63;
  const int s4 = l & 3, rq = l >> 2;
  const int sg = 4 * w + s4;
  const int cx = sg & 7;
  const int kb = 32 * sg;

  // ---- W_hh slice into VGPRs, column-permuted ----
  float wreg[4][32];
#pragma unroll
  for (int r = 0; r < 4; ++r) {
    const int rl = 4 * rq + r;
    const float* wp = Whh + (size_t)((rl >> 4) * HDIM + slot16 + (rl & 15)) * HDIM + kb;
#pragma unroll
    for (int e = 0; e < 32; ++e) wreg[r][e] = wp[e ^ cx];
  }

  // staging role (t-invariant)
  const int cl = l >> 4, m = l & 15;
  const int sgS = 4 * w + (m >> 2);
  const int sig = sgS & 7;
  int dsaddr[8];
#pragma unroll
  for (int i = 0; i < 8; ++i)
    dsaddr[i] = 132 * sgS + 4 * (8 * (m & 3) + (i ^ sig)) + cl;
  const int srcoff = cl * 512 + 128 * w + 8 * m;

  // gate-cell role
  const int qg = tid >> 6, jg = (tid >> 2) & 15, bg = tid & 3;
  const float* xq = xp + (size_t)(qg * HDIM + slot16 + jg) * BATCH + g * 4 + bg;

  // update role (wave 0)
  const int jj = l >> 2, bb = l & 3;

  float c_st = 0.f;
  if (!first && w == 0) c_st = ccur[(size_t)(g * 4 + bb) * HDIM + slot16 + jj];

  const float* hptr = &h_s[132 * sg];

#pragma unroll 1
  for (int tt = 0; tt < TCHUNK; ++tt) {
    // ---- poll + stage h(tt): data is the flag ----
    const float* src = hb + (size_t)tt * SLAB_F + g * 2048 + srcoff;
    f4 va, vb;
    int guard = 0;
    while (true) {
      asm volatile("global_load_dwordx4 %0, %2, off sc0 sc1\n\t"
                   "global_load_dwordx4 %1, %3, off sc0 sc1\n\t"
                   "s_waitcnt vmcnt(0)"
                   : "=&v"(va), "=&v"(vb) : "v"(src), "v"(src + 4) : "memory");
      const bool ok =
          __float_as_uint(va.x) != 0xFFFFFFFFu && __float_as_uint(va.y) != 0xFFFFFFFFu &&
          __float_as_uint(va.z) != 0xFFFFFFFFu && __float_as_uint(va.w) != 0xFFFFFFFFu &&
          __float_as_uint(vb.x) != 0xFFFFFFFFu && __float_as_uint(vb.y) != 0xFFFFFFFFu &&
          __float_as_uint(vb.z) != 0xFFFFFFFFu && __float_as_uint(vb.w) != 0xFFFFFFFFu;
      if (__all(ok) || ++guard > 200000) break;
      __builtin_amdgcn_s_sleep(1);
    }
    h_s[dsaddr[0]] = va.x; h_s[dsaddr[1]] = va.y;
    h_s[dsaddr[2]] = va.z; h_s[dsaddr[3]] = va.w;
    h_s[dsaddr[4]] = vb.x; h_s[dsaddr[5]] = vb.y;
    h_s[dsaddr[6]] = vb.z; h_s[dsaddr[7]] = vb.w;
    const float xpv = xq[(size_t)tt * XPSTEP];
    BARRIER();                                  // h_s(tt) ready

    // ---- partials: 4 rows x 4 chains, linear imm-offset ds_read_b128 ----
    f2 a01[4], a23[4];
#pragma unroll
    for (int r = 0; r < 4; ++r) { a01[r] = (f2){0.f, 0.f}; a23[r] = (f2){0.f, 0.f}; }
#pragma unroll
    for (int kk = 0; kk < 32; ++kk) {
      const f4 hv = *(const f4*)&hptr[4 * kk];
      const f2 h01 = {hv.x, hv.y}, h23 = {hv.z, hv.w};
#pragma unroll
      for (int r = 0; r < 4; ++r) {
        a01[r] += h01 * wreg[r][kk];
        a23[r] += h23 * wreg[r][kk];
      }
    }
#pragma unroll
    for (int r = 0; r < 4; ++r) {
      a01[r].x = quad_sum(a01[r].x); a01[r].y = quad_sum(a01[r].y);
      a23[r].x = quad_sum(a23[r].x); a23[r].y = quad_sum(a23[r].y);
    }
    f2 r01, r23;
    { const f2 v0 = (s4 & 1) ? a01[1] : a01[0];
      const f2 v1 = (s4 & 1) ? a01[3] : a01[2];
      r01 = (s4 & 2) ? v1 : v0;
      const f2 u0 = (s4 & 1) ? a23[1] : a23[0];
      const f2 u1 = (s4 & 1) ? a23[3] : a23[2];
      r23 = (s4 & 2) ? u1 : u0; }
    *(f4*)&red[(w << 8) + 4 * l] = (f4){r01.x, r01.y, r23.x, r23.y};
    BARRIER();                                  // red(tt) ready

    // ---- cross-wave reduce + xp + activation (1 cell/thread) ----
    const float pre = red[tid] + red[256 + tid] + red[512 + tid] + red[768 + tid] + xpv;
    gate_s[tid] = (qg == 2) ? tanhf(pre) : 1.f / (1.f + __expf(-pre));
    BARRIER();                                  // gates ready

    // ---- c/h update + one-way exchange store (wave 0) ----
    if (w == 0) {
      const float ig = gate_s[jj * 4 + bb];
      const float fg = gate_s[64 + jj * 4 + bb];
      const float gg = gate_s[128 + jj * 4 + bb];
      const float og = gate_s[192 + jj * 4 + bb];
      c_st = fg * c_st + ig * gg;
      const float hval = og * tanhf(c_st);
      llc_store(hb + (size_t)(tt + 1) * SLAB_F + g * 2048 + bb * 512 + slot16 + jj, hval);
      hout[(size_t)tt * (BATCH * HDIM) + (size_t)(g * 4 + bb) * HDIM + slot16 + jj] = hval;
    }
  }
  if (w == 0) ccur[(size_t)(g * 4 + bb) * HDIM + slot16 + jj] = c_st;
}

// ---------------------------------------------------------------------------
// head: logits = h2 @ W3^T + b3 ; softmax over 10. One wave per row.
// ---------------------------------------------------------------------------
__launch_bounds__(256, 2)
__global__ void head_kernel(const float* __restrict__ h2,
                            const float* __restrict__ W3,
                            const float* __restrict__ b3,
                            float* __restrict__ outp) {
  const int tid = threadIdx.x;
  const int lane = tid & 63;
  const int wv = tid >> 6;
  const int row = blockIdx.x * 4 + wv;
  const float* hrow = &h2[(size_t)row * HDIM];
  float hreg[8];
  *(float4*)&hreg[0] = *(const float4*)&hrow[lane * 8];
  *(float4*)&hreg[4] = *(const float4*)&hrow[lane * 8 + 4];
  float logit[ODIM];
#pragma unroll
  for (int o = 0; o < ODIM; ++o) {
    const float* wrow = &W3[o * HDIM + lane * 8];
    float w[8];
    *(float4*)&w[0] = *(const float4*)&wrow[0];
    *(float4*)&w[4] = *(const float4*)&wrow[4];
    float pp = 0.f;
#pragma unroll
    for (int j = 0; j < 8; ++j) pp += hreg[j] * w[j];
#pragma unroll
    for (int off = 32; off > 0; off >>= 1) pp += __shfl_xor(pp, off);
    logit[o] = pp + b3[o];
  }
  float mx = logit[0];
#pragma unroll
  for (int o = 1; o < ODIM; ++o) mx = fmaxf(mx, logit[o]);
  float ssum = 0.f;
#pragma unroll
  for (int o = 0; o < ODIM; ++o) { logit[o] = __expf(logit[o] - mx); ssum += logit[o]; }
  const float inv = 1.f / ssum;
  if (lane == 0) {
    float* dst = &outp[(size_t)row * ODIM];
#pragma unroll
    for (int o = 0; o < ODIM; ++o) dst[o] = logit[o] * inv;
  }
}

// ---------------------------------------------------------------------------
extern "C" void kernel_launch(void* const* d_in, const int* in_sizes, int n_in,
                              void* d_out, int out_size, void* d_ws, size_t ws_size,
                              hipStream_t stream) {
  const float* data  = (const float*)d_in[0];
  const float* W_ih1 = (const float*)d_in[1];
  const float* W_hh1 = (const float*)d_in[2];
  const float* b1    = (const float*)d_in[3];
  const float* W_ih2 = (const float*)d_in[4];
  const float* W_hh2 = (const float*)d_in[5];
  const float* b2    = (const float*)d_in[6];
  const float* W3    = (const float*)d_in[7];
  const float* b3    = (const float*)d_in[8];
  float* outp = (float*)d_out;

  char* ws = (char*)d_ws;
  size_t off = 0;
  float* xp1   = (float*)(ws + off); off += (size_t)TCHUNK * GDIM * BATCH * 4;     // 16MB
  float* xp2   = (float*)(ws + off); off += (size_t)TCHUNK * GDIM * BATCH * 4;     // 16MB
  float* h1c   = (float*)(ws + off); off += (size_t)TCHUNK * BATCH * HDIM * 4;     // 4MB
  float* h2c   = (float*)(ws + off); off += (size_t)TCHUNK * BATCH * HDIM * 4;     // 4MB
  float* hb1   = (float*)(ws + off); off += (size_t)(TCHUNK + 1) * SLAB_B;         // 4.26MB
  float* hb2   = (float*)(ws + off); off += (size_t)(TCHUNK + 1) * SLAB_B;
  float* ccur1 = (float*)(ws + off); off += BATCH * HDIM * 4;
  float* ccur2 = (float*)(ws + off); off += BATCH * HDIM * 4;
  if (off > ws_size) return;   // ws too small: bail visibly

  // slab 0 = h(0) = zeros; slabs 1..TCHUNK = sentinel 0xFFFFFFFF
  hipMemsetAsync(hb1, 0x00, SLAB_B, stream);
  hipMemsetAsync((char*)hb1 + SLAB_B, 0xFF, (size_t)TCHUNK * SLAB_B, stream);
  hipMemsetAsync(hb2, 0x00, SLAB_B, stream);
  hipMemsetAsync((char*)hb2 + SLAB_B, 0xFF, (size_t)TCHUNK * SLAB_B, stream);

  const dim3 pgrid(GDIM / 128, (TCHUNK * BATCH) / 128);

#define RECYCLE(HB) do {                                                    \
    hipMemcpyAsync(HB, (char*)HB + (size_t)TCHUNK * SLAB_B, SLAB_B,         \
                   hipMemcpyDeviceToDevice, stream);                        \
    hipMemsetAsync((char*)HB + SLAB_B, 0xFF, (size_t)TCHUNK * SLAB_B, stream); \
  } while (0)

  proj_kernel<IDIM><<<pgrid, 256, 0, stream>>>(data, W_ih1, b1, xp1);      // chunk 0

  for (int s = 0; s <= NCHUNK; ++s) {
    const int act1 = (s < NCHUNK);       // layer 1 processes chunk s
    const int act2 = (s >= 1);           // layer 2 processes chunk s-1
    scan_dual<<<512, 256, 0, stream>>>(
        xp1, W_hh1, h1c, hb1, ccur1, s == 0, act1,
        xp2, W_hh2, h2c, hb2, ccur2, s == 1, act2);
    if (act1) {
      RECYCLE(hb1);
      proj_kernel<HDIM><<<pgrid, 256, 0, stream>>>(h1c, W_ih2, b2, xp2);   // chunk s
      if (s + 1 < NCHUNK)
        proj_kernel<IDIM><<<pgrid, 256, 0, stream>>>(
            data + (size_t)(s + 1) * TCHUNK * BATCH * IDIM, W_ih1, b1, xp1);
    }
    if (act2) {
      if (s < NCHUNK) RECYCLE(hb2);
      head_kernel<<<(TCHUNK * BATCH) / 4, 256, 0, stream>>>(
          h2c, W3, b3, outp + (size_t)(s - 1) * TCHUNK * BATCH * ODIM);
    }
  }
#undef RECYCLE
}

// Round 15
// 9916.877 us; speedup vs baseline: 1.2130x; 1.2130x over previous
//
#include <hip/hip_runtime.h>
#include <cstdint>
#include <cstddef>

#define TCHUNK 64
#define NCHUNK 16
#define BATCH 32
#define IDIM 128
#define HDIM 512
#define GDIM 2048
#define ODIM 10
#define XPSTEP (GDIM * BATCH)
#define SLAB_F 16384            // floats per t-slab: 8 groups x 4 chains x 512
#define SLAB_B (SLAB_F * 4)

typedef float f4 __attribute__((ext_vector_type(4)));
typedef float f2 __attribute__((ext_vector_type(2)));

__device__ __forceinline__ void llc_store(float* p, float v) {
  asm volatile("global_store_dword %0, %1, off sc0 sc1" :: "v"(p), "v"(v) : "memory");
}
__device__ __forceinline__ float quad_sum(float x) {
  int t = __builtin_amdgcn_update_dpp(0, __float_as_int(x), 0xB1, 0xF, 0xF, true);
  x += __int_as_float(t);
  t = __builtin_amdgcn_update_dpp(0, __float_as_int(x), 0x4E, 0xF, 0xF, true);
  x += __int_as_float(t);
  return x;
}

#define BARRIER() do {                                                      \
    asm volatile("s_waitcnt lgkmcnt(0)" ::: "memory");                      \
    __builtin_amdgcn_sched_barrier(0);                                      \
    __builtin_amdgcn_s_barrier();                                           \
    __builtin_amdgcn_sched_barrier(0);                                      \
  } while (0)

// ---------------------------------------------------------------------------
// proj: P[tt][n][b] = sum_k X[tt*32+b][k] * W[n][k] + bias[n]
// ---------------------------------------------------------------------------
template<int K>
__launch_bounds__(256, 2)
__global__ void proj_kernel(const float* __restrict__ X,
                            const float* __restrict__ W,
                            const float* __restrict__ bias,
                            float* __restrict__ P) {
  __shared__ float Xs[8][132];
  __shared__ float Ws[8][132];
  const int tid = threadIdx.x;
  const int n0 = blockIdx.x * 128;
  const int m0 = blockIdx.y * 128;
  const int tx = tid & 15, ty = tid >> 4;
  const int lm = tid >> 1;
  const int kq = (tid & 1) * 4;
  f2 acc2[8][4];
#pragma unroll
  for (int i = 0; i < 8; ++i)
#pragma unroll
    for (int j = 0; j < 4; ++j) acc2[i][j] = (f2){0.f, 0.f};

  for (int k0 = 0; k0 < K; k0 += 8) {
    const float4 xv = *(const float4*)&X[(size_t)(m0 + lm) * K + k0 + kq];
    const float4 wv = *(const float4*)&W[(size_t)(n0 + lm) * K + k0 + kq];
    __syncthreads();
    Xs[kq + 0][lm] = xv.x; Xs[kq + 1][lm] = xv.y; Xs[kq + 2][lm] = xv.z; Xs[kq + 3][lm] = xv.w;
    Ws[kq + 0][lm] = wv.x; Ws[kq + 1][lm] = wv.y; Ws[kq + 2][lm] = wv.z; Ws[kq + 3][lm] = wv.w;
    __syncthreads();
#pragma unroll
    for (int kk = 0; kk < 8; ++kk) {
      float a[8];
      *(float4*)&a[0] = *(const float4*)&Xs[kk][ty * 8];
      *(float4*)&a[4] = *(const float4*)&Xs[kk][ty * 8 + 4];
      f2 b2[4];
#pragma unroll
      for (int jp = 0; jp < 4; ++jp) b2[jp] = *(const f2*)&Ws[kk][tx * 8 + 2 * jp];
#pragma unroll
      for (int i = 0; i < 8; ++i)
#pragma unroll
        for (int jp = 0; jp < 4; ++jp) acc2[i][jp] += b2[jp] * a[i];
    }
  }
  const int mb = m0 + ty * 8;
  const int t  = mb >> 5;
  const int b0 = mb & 31;
#pragma unroll
  for (int j = 0; j < 8; ++j) {
    const int n = n0 + tx * 8 + j;
    const float bj = bias[n];
    float* dst = &P[((size_t)t * GDIM + n) * BATCH + b0];
#pragma unroll
    for (int i = 0; i < 8; ++i)
      dst[i] = ((j & 1) ? acc2[i][j >> 1].y : acc2[i][j >> 1].x) + bj;
  }
}

// ---------------------------------------------------------------------------
// scan_dual: TWO verbatim R10 engines per CU. 512 blocks; blocks 0..255 run
// layer 1 (chunk s), 256..511 run layer 2 (chunk s-1). __launch_bounds__
// (256,1) like R10 -> compiler allocates ~156 VGPR (NO spill of the 128-float
// wreg); HW then co-schedules 2 blocks/CU from actual usage (156<=256 VGPR,
// 13.6KB LDS). Layers fully uncoupled (own W, slabs, sentinels, polls); the
// CU scheduler fills one layer's poll/barrier stalls with the other's waves.
// Worst case (1 block/CU) = serialized layers ~= R10; no deadlock possible.
// ---------------------------------------------------------------------------
__launch_bounds__(256, 1)
__global__ void scan_dual(const float* __restrict__ xp1, const float* __restrict__ Whh1,
                          float* __restrict__ hout1, float* __restrict__ hb1,
                          float* __restrict__ ccur1, int first1, int act1,
                          const float* __restrict__ xp2, const float* __restrict__ Whh2,
                          float* __restrict__ hout2, float* __restrict__ hb2,
                          float* __restrict__ ccur2, int first2, int act2) {
  __shared__ float h_s[2112];       // 16 slices x 132 floats (4-float pad/slice)
  __shared__ float red[1024];
  __shared__ float gate_s[256];

  const int bid = blockIdx.x;
  const int lay = bid >> 8;
  if (!(lay ? act2 : act1)) return;
  const float* xp  = lay ? xp2  : xp1;
  const float* Whh = lay ? Whh2 : Whh1;
  float* hout = lay ? hout2 : hout1;
  float* hb   = lay ? hb2   : hb1;
  float* ccur = lay ? ccur2 : ccur1;
  const int first = lay ? first2 : first1;

  const int tid = threadIdx.x;
  const int bidl = bid & 255;
  const int g = bidl & 7, rank = bidl >> 3, slot16 = rank * 16;
  const int w = tid >> 6, l = tid & 63;
  const int s4 = l & 3, rq = l >> 2;
  const int sg = 4 * w + s4;
  const int cx = sg & 7;
  const int kb = 32 * sg;

  // ---- W_hh slice into VGPRs, column-permuted ----
  float wreg[4][32];
#pragma unroll
  for (int r = 0; r < 4; ++r) {
    const int rl = 4 * rq + r;
    const float* wp = Whh + (size_t)((rl >> 4) * HDIM + slot16 + (rl & 15)) * HDIM + kb;
#pragma unroll
    for (int e = 0; e < 32; ++e) wreg[r][e] = wp[e ^ cx];
  }

  // staging role (t-invariant)
  const int cl = l >> 4, m = l & 15;
  const int sgS = 4 * w + (m >> 2);
  const int sig = sgS & 7;
  int dsaddr[8];
#pragma unroll
  for (int i = 0; i < 8; ++i)
    dsaddr[i] = 132 * sgS + 4 * (8 * (m & 3) + (i ^ sig)) + cl;
  const int srcoff = cl * 512 + 128 * w + 8 * m;

  // gate-cell role
  const int qg = tid >> 6, jg = (tid >> 2) & 15, bg = tid & 3;
  const float* xq = xp + (size_t)(qg * HDIM + slot16 + jg) * BATCH + g * 4 + bg;

  // update role (wave 0)
  const int jj = l >> 2, bb = l & 3;

  float c_st = 0.f;
  if (!first && w == 0) c_st = ccur[(size_t)(g * 4 + bb) * HDIM + slot16 + jj];

  const float* hptr = &h_s[132 * sg];

#pragma unroll 1
  for (int tt = 0; tt < TCHUNK; ++tt) {
    // ---- poll + stage h(tt): data is the flag ----
    const float* src = hb + (size_t)tt * SLAB_F + g * 2048 + srcoff;
    f4 va, vb;
    int guard = 0;
    while (true) {
      asm volatile("global_load_dwordx4 %0, %2, off sc0 sc1\n\t"
                   "global_load_dwordx4 %1, %3, off sc0 sc1\n\t"
                   "s_waitcnt vmcnt(0)"
                   : "=&v"(va), "=&v"(vb) : "v"(src), "v"(src + 4) : "memory");
      const bool ok =
          __float_as_uint(va.x) != 0xFFFFFFFFu && __float_as_uint(va.y) != 0xFFFFFFFFu &&
          __float_as_uint(va.z) != 0xFFFFFFFFu && __float_as_uint(va.w) != 0xFFFFFFFFu &&
          __float_as_uint(vb.x) != 0xFFFFFFFFu && __float_as_uint(vb.y) != 0xFFFFFFFFu &&
          __float_as_uint(vb.z) != 0xFFFFFFFFu && __float_as_uint(vb.w) != 0xFFFFFFFFu;
      if (__all(ok) || ++guard > 500000) break;
      __builtin_amdgcn_s_sleep(1);
    }
    h_s[dsaddr[0]] = va.x; h_s[dsaddr[1]] = va.y;
    h_s[dsaddr[2]] = va.z; h_s[dsaddr[3]] = va.w;
    h_s[dsaddr[4]] = vb.x; h_s[dsaddr[5]] = vb.y;
    h_s[dsaddr[6]] = vb.z; h_s[dsaddr[7]] = vb.w;
    const float xpv = xq[(size_t)tt * XPSTEP];
    BARRIER();                                  // h_s(tt) ready

    // ---- partials: 4 rows x 4 chains, linear imm-offset ds_read_b128 ----
    f2 a01[4], a23[4];
#pragma unroll
    for (int r = 0; r < 4; ++r) { a01[r] = (f2){0.f, 0.f}; a23[r] = (f2){0.f, 0.f}; }
#pragma unroll
    for (int kk = 0; kk < 32; ++kk) {
      const f4 hv = *(const f4*)&hptr[4 * kk];
      const f2 h01 = {hv.x, hv.y}, h23 = {hv.z, hv.w};
#pragma unroll
      for (int r = 0; r < 4; ++r) {
        a01[r] += h01 * wreg[r][kk];
        a23[r] += h23 * wreg[r][kk];
      }
    }
#pragma unroll
    for (int r = 0; r < 4; ++r) {
      a01[r].x = quad_sum(a01[r].x); a01[r].y = quad_sum(a01[r].y);
      a23[r].x = quad_sum(a23[r].x); a23[r].y = quad_sum(a23[r].y);
    }
    f2 r01, r23;
    { const f2 v0 = (s4 & 1) ? a01[1] : a01[0];
      const f2 v1 = (s4 & 1) ? a01[3] : a01[2];
      r01 = (s4 & 2) ? v1 : v0;
      const f2 u0 = (s4 & 1) ? a23[1] : a23[0];
      const f2 u1 = (s4 & 1) ? a23[3] : a23[2];
      r23 = (s4 & 2) ? u1 : u0; }
    *(f4*)&red[(w << 8) + 4 * l] = (f4){r01.x, r01.y, r23.x, r23.y};
    BARRIER();                                  // red(tt) ready

    // ---- cross-wave reduce + xp + activation (1 cell/thread) ----
    const float pre = red[tid] + red[256 + tid] + red[512 + tid] + red[768 + tid] + xpv;
    gate_s[tid] = (qg == 2) ? tanhf(pre) : 1.f / (1.f + __expf(-pre));
    BARRIER();                                  // gates ready

    // ---- c/h update + one-way exchange store (wave 0) ----
    if (w == 0) {
      const float ig = gate_s[jj * 4 + bb];
      const float fg = gate_s[64 + jj * 4 + bb];
      const float gg = gate_s[128 + jj * 4 + bb];
      const float og = gate_s[192 + jj * 4 + bb];
      c_st = fg * c_st + ig * gg;
      const float hval = og * tanhf(c_st);
      llc_store(hb + (size_t)(tt + 1) * SLAB_F + g * 2048 + bb * 512 + slot16 + jj, hval);
      hout[(size_t)tt * (BATCH * HDIM) + (size_t)(g * 4 + bb) * HDIM + slot16 + jj] = hval;
    }
  }
  if (w == 0) ccur[(size_t)(g * 4 + bb) * HDIM + slot16 + jj] = c_st;
}

// ---------------------------------------------------------------------------
// head: logits = h2 @ W3^T + b3 ; softmax over 10. One wave per row.
// ---------------------------------------------------------------------------
__launch_bounds__(256, 2)
__global__ void head_kernel(const float* __restrict__ h2,
                            const float* __restrict__ W3,
                            const float* __restrict__ b3,
                            float* __restrict__ outp) {
  const int tid = threadIdx.x;
  const int lane = tid & 63;
  const int wv = tid >> 6;
  const int row = blockIdx.x * 4 + wv;
  const float* hrow = &h2[(size_t)row * HDIM];
  float hreg[8];
  *(float4*)&hreg[0] = *(const float4*)&hrow[lane * 8];
  *(float4*)&hreg[4] = *(const float4*)&hrow[lane * 8 + 4];
  float logit[ODIM];
#pragma unroll
  for (int o = 0; o < ODIM; ++o) {
    const float* wrow = &W3[o * HDIM + lane * 8];
    float w[8];
    *(float4*)&w[0] = *(const float4*)&wrow[0];
    *(float4*)&w[4] = *(const float4*)&wrow[4];
    float pp = 0.f;
#pragma unroll
    for (int j = 0; j < 8; ++j) pp += hreg[j] * w[j];
#pragma unroll
    for (int off = 32; off > 0; off >>= 1) pp += __shfl_xor(pp, off);
    logit[o] = pp + b3[o];
  }
  float mx = logit[0];
#pragma unroll
  for (int o = 1; o < ODIM; ++o) mx = fmaxf(mx, logit[o]);
  float ssum = 0.f;
#pragma unroll
  for (int o = 0; o < ODIM; ++o) { logit[o] = __expf(logit[o] - mx); ssum += logit[o]; }
  const float inv = 1.f / ssum;
  if (lane == 0) {
    float* dst = &outp[(size_t)row * ODIM];
#pragma unroll
    for (int o = 0; o < ODIM; ++o) dst[o] = logit[o] * inv;
  }
}

// ---------------------------------------------------------------------------
extern "C" void kernel_launch(void* const* d_in, const int* in_sizes, int n_in,
                              void* d_out, int out_size, void* d_ws, size_t ws_size,
                              hipStream_t stream) {
  const float* data  = (const float*)d_in[0];
  const float* W_ih1 = (const float*)d_in[1];
  const float* W_hh1 = (const float*)d_in[2];
  const float* b1    = (const float*)d_in[3];
  const float* W_ih2 = (const float*)d_in[4];
  const float* W_hh2 = (const float*)d_in[5];
  const float* b2    = (const float*)d_in[6];
  const float* W3    = (const float*)d_in[7];
  const float* b3    = (const float*)d_in[8];
  float* outp = (float*)d_out;

  char* ws = (char*)d_ws;
  size_t off = 0;
  float* xp1   = (float*)(ws + off); off += (size_t)TCHUNK * GDIM * BATCH * 4;     // 16MB
  float* xp2   = (float*)(ws + off); off += (size_t)TCHUNK * GDIM * BATCH * 4;     // 16MB
  float* h1c   = (float*)(ws + off); off += (size_t)TCHUNK * BATCH * HDIM * 4;     // 4MB
  float* h2c   = (float*)(ws + off); off += (size_t)TCHUNK * BATCH * HDIM * 4;     // 4MB
  float* hb1   = (float*)(ws + off); off += (size_t)(TCHUNK + 1) * SLAB_B;         // 4.26MB
  float* hb2   = (float*)(ws + off); off += (size_t)(TCHUNK + 1) * SLAB_B;
  float* ccur1 = (float*)(ws + off); off += BATCH * HDIM * 4;
  float* ccur2 = (float*)(ws + off); off += BATCH * HDIM * 4;
  if (off > ws_size) return;   // ws too small: bail visibly

  // slab 0 = h(0) = zeros; slabs 1..TCHUNK = sentinel 0xFFFFFFFF
  hipMemsetAsync(hb1, 0x00, SLAB_B, stream);
  hipMemsetAsync((char*)hb1 + SLAB_B, 0xFF, (size_t)TCHUNK * SLAB_B, stream);
  hipMemsetAsync(hb2, 0x00, SLAB_B, stream);
  hipMemsetAsync((char*)hb2 + SLAB_B, 0xFF, (size_t)TCHUNK * SLAB_B, stream);

  const dim3 pgrid(GDIM / 128, (TCHUNK * BATCH) / 128);

#define RECYCLE(HB) do {                                                    \
    hipMemcpyAsync(HB, (char*)HB + (size_t)TCHUNK * SLAB_B, SLAB_B,         \
                   hipMemcpyDeviceToDevice, stream);                        \
    hipMemsetAsync((char*)HB + SLAB_B, 0xFF, (size_t)TCHUNK * SLAB_B, stream); \
  } while (0)

  proj_kernel<IDIM><<<pgrid, 256, 0, stream>>>(data, W_ih1, b1, xp1);      // chunk 0

  for (int s = 0; s <= NCHUNK; ++s) {
    const int act1 = (s < NCHUNK);       // layer 1 processes chunk s
    const int act2 = (s >= 1);           // layer 2 processes chunk s-1
    scan_dual<<<512, 256, 0, stream>>>(
        xp1, W_hh1, h1c, hb1, ccur1, s == 0, act1,
        xp2, W_hh2, h2c, hb2, ccur2, s == 1, act2);
    if (act1) {
      RECYCLE(hb1);
      proj_kernel<HDIM><<<pgrid, 256, 0, stream>>>(h1c, W_ih2, b2, xp2);   // chunk s
      if (s + 1 < NCHUNK)
        proj_kernel<IDIM><<<pgrid, 256, 0, stream>>>(
            data + (size_t)(s + 1) * TCHUNK * BATCH * IDIM, W_ih1, b1, xp1);
    }
    if (act2) {
      if (s < NCHUNK) RECYCLE(hb2);
      head_kernel<<<(TCHUNK * BATCH) / 4, 256, 0, stream>>>(
          h2c, W3, b3, outp + (size_t)(s - 1) * TCHUNK * BATCH * ODIM);
    }
  }
#undef RECYCLE
}

// Round 16
// 9903.036 us; speedup vs baseline: 1.2147x; 1.0014x over previous
//
#include <hip/hip_runtime.h>
#include <cstdint>
#include <cstddef>

#define TCHUNK 64
#define NCHUNK 16
#define BATCH 32
#define IDIM 128
#define HDIM 512
#define GDIM 2048
#define ODIM 10
#define XPSTEP (GDIM * BATCH)
#define SLAB_F 16384            // floats per t-slab: 8 groups x 4 chains x 512
#define SLAB_B (SLAB_F * 4)

typedef float f4 __attribute__((ext_vector_type(4)));
typedef float f2 __attribute__((ext_vector_type(2)));

__device__ __forceinline__ void llc_store(float* p, float v) {
  asm volatile("global_store_dword %0, %1, off sc0 sc1" :: "v"(p), "v"(v) : "memory");
}
__device__ __forceinline__ float quad_sum(float x) {
  int t = __builtin_amdgcn_update_dpp(0, __float_as_int(x), 0xB1, 0xF, 0xF, true);
  x += __int_as_float(t);
  t = __builtin_amdgcn_update_dpp(0, __float_as_int(x), 0x4E, 0xF, 0xF, true);
  x += __int_as_float(t);
  return x;
}

#define BARRIER() do {                                                      \
    asm volatile("s_waitcnt lgkmcnt(0)" ::: "memory");                      \
    __builtin_amdgcn_sched_barrier(0);                                      \
    __builtin_amdgcn_s_barrier();                                           \
    __builtin_amdgcn_sched_barrier(0);                                      \
  } while (0)

// ---------------------------------------------------------------------------
// proj: P[tt][n][b] = sum_k X[tt*32+b][k] * W[n][k] + bias[n]
// ---------------------------------------------------------------------------
template<int K>
__launch_bounds__(256, 2)
__global__ void proj_kernel(const float* __restrict__ X,
                            const float* __restrict__ W,
                            const float* __restrict__ bias,
                            float* __restrict__ P) {
  __shared__ float Xs[8][132];
  __shared__ float Ws[8][132];
  const int tid = threadIdx.x;
  const int n0 = blockIdx.x * 128;
  const int m0 = blockIdx.y * 128;
  const int tx = tid & 15, ty = tid >> 4;
  const int lm = tid >> 1;
  const int kq = (tid & 1) * 4;
  f2 acc2[8][4];
#pragma unroll
  for (int i = 0; i < 8; ++i)
#pragma unroll
    for (int j = 0; j < 4; ++j) acc2[i][j] = (f2){0.f, 0.f};

  for (int k0 = 0; k0 < K; k0 += 8) {
    const float4 xv = *(const float4*)&X[(size_t)(m0 + lm) * K + k0 + kq];
    const float4 wv = *(const float4*)&W[(size_t)(n0 + lm) * K + k0 + kq];
    __syncthreads();
    Xs[kq + 0][lm] = xv.x; Xs[kq + 1][lm] = xv.y; Xs[kq + 2][lm] = xv.z; Xs[kq + 3][lm] = xv.w;
    Ws[kq + 0][lm] = wv.x; Ws[kq + 1][lm] = wv.y; Ws[kq + 2][lm] = wv.z; Ws[kq + 3][lm] = wv.w;
    __syncthreads();
#pragma unroll
    for (int kk = 0; kk < 8; ++kk) {
      float a[8];
      *(float4*)&a[0] = *(const float4*)&Xs[kk][ty * 8];
      *(float4*)&a[4] = *(const float4*)&Xs[kk][ty * 8 + 4];
      f2 b2[4];
#pragma unroll
      for (int jp = 0; jp < 4; ++jp) b2[jp] = *(const f2*)&Ws[kk][tx * 8 + 2 * jp];
#pragma unroll
      for (int i = 0; i < 8; ++i)
#pragma unroll
        for (int jp = 0; jp < 4; ++jp) acc2[i][jp] += b2[jp] * a[i];
    }
  }
  const int mb = m0 + ty * 8;
  const int t  = mb >> 5;
  const int b0 = mb & 31;
#pragma unroll
  for (int j = 0; j < 8; ++j) {
    const int n = n0 + tx * 8 + j;
    const float bj = bias[n];
    float* dst = &P[((size_t)t * GDIM + n) * BATCH + b0];
#pragma unroll
    for (int i = 0; i < 8; ++i)
      dst[i] = ((j & 1) ? acc2[i][j >> 1].y : acc2[i][j >> 1].x) + bj;
  }
}

// ---------------------------------------------------------------------------
// scan_dual: TWO verbatim R10 engines per CU. 512 blocks; blocks 0..255 run
// layer 1 (chunk s), 256..511 run layer 2 (chunk s-1). NO waves-per-EU
// attribute (R14's (256,2) capped VGPR->128 = spill; R15's (256,1) pinned
// 1 block/CU = serial layers). flat_work_group_size fixes the block size
// only; compiler allocates ~156 VGPR freely, HW then co-schedules 2
// blocks/CU from actual usage (156 VGPR <= 256 step, 13.8KB LDS). Layers
// fully uncoupled (own W, slabs, sentinels, polls); each layer's waves fill
// the other's poll/barrier stalls. Worst case = serialized layers ~= R15.
// ---------------------------------------------------------------------------
__attribute__((amdgpu_flat_work_group_size(256, 256)))
__global__ void scan_dual(const float* __restrict__ xp1, const float* __restrict__ Whh1,
                          float* __restrict__ hout1, float* __restrict__ hb1,
                          float* __restrict__ ccur1, int first1, int act1,
                          const float* __restrict__ xp2, const float* __restrict__ Whh2,
                          float* __restrict__ hout2, float* __restrict__ hb2,
                          float* __restrict__ ccur2, int first2, int act2) {
  __shared__ float h_s[2112];       // 16 slices x 132 floats (4-float pad/slice)
  __shared__ float red[1024];
  __shared__ float gate_s[256];

  const int bid = blockIdx.x;
  const int lay = bid >> 8;
  if (!(lay ? act2 : act1)) return;
  const float* xp  = lay ? xp2  : xp1;
  const float* Whh = lay ? Whh2 : Whh1;
  float* hout = lay ? hout2 : hout1;
  float* hb   = lay ? hb2   : hb1;
  float* ccur = lay ? ccur2 : ccur1;
  const int first = lay ? first2 : first1;

  const int tid = threadIdx.x;
  const int bidl = bid & 255;
  const int g = bidl & 7, rank = bidl >> 3, slot16 = rank * 16;
  const int w = tid >> 6, l = tid & 63;
  const int s4 = l & 3, rq = l >> 2;
  const int sg = 4 * w + s4;
  const int cx = sg & 7;
  const int kb = 32 * sg;

  // ---- W_hh slice into VGPRs, column-permuted ----
  float wreg[4][32];
#pragma unroll
  for (int r = 0; r < 4; ++r) {
    const int rl = 4 * rq + r;
    const float* wp = Whh + (size_t)((rl >> 4) * HDIM + slot16 + (rl & 15)) * HDIM + kb;
#pragma unroll
    for (int e = 0; e < 32; ++e) wreg[r][e] = wp[e ^ cx];
  }

  // staging role (t-invariant)
  const int cl = l >> 4, m = l & 15;
  const int sgS = 4 * w + (m >> 2);
  const int sig = sgS & 7;
  int dsaddr[8];
#pragma unroll
  for (int i = 0; i < 8; ++i)
    dsaddr[i] = 132 * sgS + 4 * (8 * (m & 3) + (i ^ sig)) + cl;
  const int srcoff = cl * 512 + 128 * w + 8 * m;

  // gate-cell role
  const int qg = tid >> 6, jg = (tid >> 2) & 15, bg = tid & 3;
  const float* xq = xp + (size_t)(qg * HDIM + slot16 + jg) * BATCH + g * 4 + bg;

  // update role (wave 0)
  const int jj = l >> 2, bb = l & 3;

  float c_st = 0.f;
  if (!first && w == 0) c_st = ccur[(size_t)(g * 4 + bb) * HDIM + slot16 + jj];

  const float* hptr = &h_s[132 * sg];

#pragma unroll 1
  for (int tt = 0; tt < TCHUNK; ++tt) {
    // ---- poll + stage h(tt): data is the flag ----
    const float* src = hb + (size_t)tt * SLAB_F + g * 2048 + srcoff;
    f4 va, vb;
    int guard = 0;
    while (true) {
      asm volatile("global_load_dwordx4 %0, %2, off sc0 sc1\n\t"
                   "global_load_dwordx4 %1, %3, off sc0 sc1\n\t"
                   "s_waitcnt vmcnt(0)"
                   : "=&v"(va), "=&v"(vb) : "v"(src), "v"(src + 4) : "memory");
      const bool ok =
          __float_as_uint(va.x) != 0xFFFFFFFFu && __float_as_uint(va.y) != 0xFFFFFFFFu &&
          __float_as_uint(va.z) != 0xFFFFFFFFu && __float_as_uint(va.w) != 0xFFFFFFFFu &&
          __float_as_uint(vb.x) != 0xFFFFFFFFu && __float_as_uint(vb.y) != 0xFFFFFFFFu &&
          __float_as_uint(vb.z) != 0xFFFFFFFFu && __float_as_uint(vb.w) != 0xFFFFFFFFu;
      if (__all(ok) || ++guard > 500000) break;
      __builtin_amdgcn_s_sleep(1);
    }
    h_s[dsaddr[0]] = va.x; h_s[dsaddr[1]] = va.y;
    h_s[dsaddr[2]] = va.z; h_s[dsaddr[3]] = va.w;
    h_s[dsaddr[4]] = vb.x; h_s[dsaddr[5]] = vb.y;
    h_s[dsaddr[6]] = vb.z; h_s[dsaddr[7]] = vb.w;
    const float xpv = xq[(size_t)tt * XPSTEP];
    BARRIER();                                  // h_s(tt) ready

    // ---- partials: 4 rows x 4 chains, linear imm-offset ds_read_b128 ----
    f2 a01[4], a23[4];
#pragma unroll
    for (int r = 0; r < 4; ++r) { a01[r] = (f2){0.f, 0.f}; a23[r] = (f2){0.f, 0.f}; }
#pragma unroll
    for (int kk = 0; kk < 32; ++kk) {
      const f4 hv = *(const f4*)&hptr[4 * kk];
      const f2 h01 = {hv.x, hv.y}, h23 = {hv.z, hv.w};
#pragma unroll
      for (int r = 0; r < 4; ++r) {
        a01[r] += h01 * wreg[r][kk];
        a23[r] += h23 * wreg[r][kk];
      }
    }
#pragma unroll
    for (int r = 0; r < 4; ++r) {
      a01[r].x = quad_sum(a01[r].x); a01[r].y = quad_sum(a01[r].y);
      a23[r].x = quad_sum(a23[r].x); a23[r].y = quad_sum(a23[r].y);
    }
    f2 r01, r23;
    { const f2 v0 = (s4 & 1) ? a01[1] : a01[0];
      const f2 v1 = (s4 & 1) ? a01[3] : a01[2];
      r01 = (s4 & 2) ? v1 : v0;
      const f2 u0 = (s4 & 1) ? a23[1] : a23[0];
      const f2 u1 = (s4 & 1) ? a23[3] : a23[2];
      r23 = (s4 & 2) ? u1 : u0; }
    *(f4*)&red[(w << 8) + 4 * l] = (f4){r01.x, r01.y, r23.x, r23.y};
    BARRIER();                                  // red(tt) ready

    // ---- cross-wave reduce + xp + activation (1 cell/thread) ----
    const float pre = red[tid] + red[256 + tid] + red[512 + tid] + red[768 + tid] + xpv;
    gate_s[tid] = (qg == 2) ? tanhf(pre) : 1.f / (1.f + __expf(-pre));
    BARRIER();                                  // gates ready

    // ---- c/h update + one-way exchange store (wave 0) ----
    if (w == 0) {
      const float ig = gate_s[jj * 4 + bb];
      const float fg = gate_s[64 + jj * 4 + bb];
      const float gg = gate_s[128 + jj * 4 + bb];
      const float og = gate_s[192 + jj * 4 + bb];
      c_st = fg * c_st + ig * gg;
      const float hval = og * tanhf(c_st);
      llc_store(hb + (size_t)(tt + 1) * SLAB_F + g * 2048 + bb * 512 + slot16 + jj, hval);
      hout[(size_t)tt * (BATCH * HDIM) + (size_t)(g * 4 + bb) * HDIM + slot16 + jj] = hval;
    }
  }
  if (w == 0) ccur[(size_t)(g * 4 + bb) * HDIM + slot16 + jj] = c_st;
}

// ---------------------------------------------------------------------------
// head: logits = h2 @ W3^T + b3 ; softmax over 10. One wave per row.
// ---------------------------------------------------------------------------
__launch_bounds__(256, 2)
__global__ void head_kernel(const float* __restrict__ h2,
                            const float* __restrict__ W3,
                            const float* __restrict__ b3,
                            float* __restrict__ outp) {
  const int tid = threadIdx.x;
  const int lane = tid & 63;
  const int wv = tid >> 6;
  const int row = blockIdx.x * 4 + wv;
  const float* hrow = &h2[(size_t)row * HDIM];
  float hreg[8];
  *(float4*)&hreg[0] = *(const float4*)&hrow[lane * 8];
  *(float4*)&hreg[4] = *(const float4*)&hrow[lane * 8 + 4];
  float logit[ODIM];
#pragma unroll
  for (int o = 0; o < ODIM; ++o) {
    const float* wrow = &W3[o * HDIM + lane * 8];
    float w[8];
    *(float4*)&w[0] = *(const float4*)&wrow[0];
    *(float4*)&w[4] = *(const float4*)&wrow[4];
    float pp = 0.f;
#pragma unroll
    for (int j = 0; j < 8; ++j) pp += hreg[j] * w[j];
#pragma unroll
    for (int off = 32; off > 0; off >>= 1) pp += __shfl_xor(pp, off);
    logit[o] = pp + b3[o];
  }
  float mx = logit[0];
#pragma unroll
  for (int o = 1; o < ODIM; ++o) mx = fmaxf(mx, logit[o]);
  float ssum = 0.f;
#pragma unroll
  for (int o = 0; o < ODIM; ++o) { logit[o] = __expf(logit[o] - mx); ssum += logit[o]; }
  const float inv = 1.f / ssum;
  if (lane == 0) {
    float* dst = &outp[(size_t)row * ODIM];
#pragma unroll
    for (int o = 0; o < ODIM; ++o) dst[o] = logit[o] * inv;
  }
}

// ---------------------------------------------------------------------------
extern "C" void kernel_launch(void* const* d_in, const int* in_sizes, int n_in,
                              void* d_out, int out_size, void* d_ws, size_t ws_size,
                              hipStream_t stream) {
  const float* data  = (const float*)d_in[0];
  const float* W_ih1 = (const float*)d_in[1];
  const float* W_hh1 = (const float*)d_in[2];
  const float* b1    = (const float*)d_in[3];
  const float* W_ih2 = (const float*)d_in[4];
  const float* W_hh2 = (const float*)d_in[5];
  const float* b2    = (const float*)d_in[6];
  const float* W3    = (const float*)d_in[7];
  const float* b3    = (const float*)d_in[8];
  float* outp = (float*)d_out;

  char* ws = (char*)d_ws;
  size_t off = 0;
  float* xp1   = (float*)(ws + off); off += (size_t)TCHUNK * GDIM * BATCH * 4;     // 16MB
  float* xp2   = (float*)(ws + off); off += (size_t)TCHUNK * GDIM * BATCH * 4;     // 16MB
  float* h1c   = (float*)(ws + off); off += (size_t)TCHUNK * BATCH * HDIM * 4;     // 4MB
  float* h2c   = (float*)(ws + off); off += (size_t)TCHUNK * BATCH * HDIM * 4;     // 4MB
  float* hb1   = (float*)(ws + off); off += (size_t)(TCHUNK + 1) * SLAB_B;         // 4.26MB
  float* hb2   = (float*)(ws + off); off += (size_t)(TCHUNK + 1) * SLAB_B;
  float* ccur1 = (float*)(ws + off); off += BATCH * HDIM * 4;
  float* ccur2 = (float*)(ws + off); off += BATCH * HDIM * 4;
  if (off > ws_size) return;   // ws too small: bail visibly

  // slab 0 = h(0) = zeros; slabs 1..TCHUNK = sentinel 0xFFFFFFFF
  hipMemsetAsync(hb1, 0x00, SLAB_B, stream);
  hipMemsetAsync((char*)hb1 + SLAB_B, 0xFF, (size_t)TCHUNK * SLAB_B, stream);
  hipMemsetAsync(hb2, 0x00, SLAB_B, stream);
  hipMemsetAsync((char*)hb2 + SLAB_B, 0xFF, (size_t)TCHUNK * SLAB_B, stream);

  const dim3 pgrid(GDIM / 128, (TCHUNK * BATCH) / 128);

#define RECYCLE(HB) do {                                                    \
    hipMemcpyAsync(HB, (char*)HB + (size_t)TCHUNK * SLAB_B, SLAB_B,         \
                   hipMemcpyDeviceToDevice, stream);                        \
    hipMemsetAsync((char*)HB + SLAB_B, 0xFF, (size_t)TCHUNK * SLAB_B, stream); \
  } while (0)

  proj_kernel<IDIM><<<pgrid, 256, 0, stream>>>(data, W_ih1, b1, xp1);      // chunk 0

  for (int s = 0; s <= NCHUNK; ++s) {
    const int act1 = (s < NCHUNK);       // layer 1 processes chunk s
    const int act2 = (s >= 1);           // layer 2 processes chunk s-1
    scan_dual<<<512, 256, 0, stream>>>(
        xp1, W_hh1, h1c, hb1, ccur1, s == 0, act1,
        xp2, W_hh2, h2c, hb2, ccur2, s == 1, act2);
    if (act1) {
      RECYCLE(hb1);
      proj_kernel<HDIM><<<pgrid, 256, 0, stream>>>(h1c, W_ih2, b2, xp2);   // chunk s
      if (s + 1 < NCHUNK)
        proj_kernel<IDIM><<<pgrid, 256, 0, stream>>>(
            data + (size_t)(s + 1) * TCHUNK * BATCH * IDIM, W_ih1, b1, xp1);
    }
    if (act2) {
      if (s < NCHUNK) RECYCLE(hb2);
      head_kernel<<<(TCHUNK * BATCH) / 4, 256, 0, stream>>>(
          h2c, W3, b3, outp + (size_t)(s - 1) * TCHUNK * BATCH * ODIM);
    }
  }
#undef RECYCLE
}

// Round 17
// 9675.754 us; speedup vs baseline: 1.2433x; 1.0235x over previous
//
#include <hip/hip_runtime.h>
#include <cstdint>
#include <cstddef>

#define TCHUNK 128
#define NCHUNK 8
#define BATCH 32
#define IDIM 128
#define HDIM 512
#define GDIM 2048
#define ODIM 10
#define NBLK 256
#define XPSTEP (GDIM * BATCH)
#define SLAB_F 16384            // floats per t-slab: 8 groups x 4 chains x 512
#define SLAB_B (SLAB_F * 4)

typedef float f4 __attribute__((ext_vector_type(4)));
typedef float f2 __attribute__((ext_vector_type(2)));

// LLC-visible store (sc0 sc1): one-way, placement-independent truth copy
__device__ __forceinline__ void llc_store(float* p, float v) {
  asm volatile("global_store_dword %0, %1, off sc0 sc1" :: "v"(p), "v"(v) : "memory");
}
__device__ __forceinline__ float quad_sum(float x) {
  int t = __builtin_amdgcn_update_dpp(0, __float_as_int(x), 0xB1, 0xF, 0xF, true);
  x += __int_as_float(t);
  t = __builtin_amdgcn_update_dpp(0, __float_as_int(x), 0x4E, 0xF, 0xF, true);
  x += __int_as_float(t);
  return x;
}

#define BARRIER() do {                                                      \
    asm volatile("s_waitcnt lgkmcnt(0)" ::: "memory");                      \
    __builtin_amdgcn_sched_barrier(0);                                      \
    __builtin_amdgcn_s_barrier();                                           \
    __builtin_amdgcn_sched_barrier(0);                                      \
  } while (0)

#define OK8(A, B) (__float_as_uint(A.x) != 0xFFFFFFFFu && __float_as_uint(A.y) != 0xFFFFFFFFu && \
                   __float_as_uint(A.z) != 0xFFFFFFFFu && __float_as_uint(A.w) != 0xFFFFFFFFu && \
                   __float_as_uint(B.x) != 0xFFFFFFFFu && __float_as_uint(B.y) != 0xFFFFFFFFu && \
                   __float_as_uint(B.z) != 0xFFFFFFFFu && __float_as_uint(B.w) != 0xFFFFFFFFu)

// ---------------------------------------------------------------------------
// proj: P[tt][n][b] = sum_k X[tt*32+b][k] * W[n][k] + bias[n]
// ---------------------------------------------------------------------------
template<int K>
__launch_bounds__(256, 2)
__global__ void proj_kernel(const float* __restrict__ X,
                            const float* __restrict__ W,
                            const float* __restrict__ bias,
                            float* __restrict__ P) {
  __shared__ float Xs[8][132];
  __shared__ float Ws[8][132];
  const int tid = threadIdx.x;
  const int n0 = blockIdx.x * 128;
  const int m0 = blockIdx.y * 128;
  const int tx = tid & 15, ty = tid >> 4;
  const int lm = tid >> 1;
  const int kq = (tid & 1) * 4;
  f2 acc2[8][4];
#pragma unroll
  for (int i = 0; i < 8; ++i)
#pragma unroll
    for (int j = 0; j < 4; ++j) acc2[i][j] = (f2){0.f, 0.f};

  for (int k0 = 0; k0 < K; k0 += 8) {
    const float4 xv = *(const float4*)&X[(size_t)(m0 + lm) * K + k0 + kq];
    const float4 wv = *(const float4*)&W[(size_t)(n0 + lm) * K + k0 + kq];
    __syncthreads();
    Xs[kq + 0][lm] = xv.x; Xs[kq + 1][lm] = xv.y; Xs[kq + 2][lm] = xv.z; Xs[kq + 3][lm] = xv.w;
    Ws[kq + 0][lm] = wv.x; Ws[kq + 1][lm] = wv.y; Ws[kq + 2][lm] = wv.z; Ws[kq + 3][lm] = wv.w;
    __syncthreads();
#pragma unroll
    for (int kk = 0; kk < 8; ++kk) {
      float a[8];
      *(float4*)&a[0] = *(const float4*)&Xs[kk][ty * 8];
      *(float4*)&a[4] = *(const float4*)&Xs[kk][ty * 8 + 4];
      f2 b2[4];
#pragma unroll
      for (int jp = 0; jp < 4; ++jp) b2[jp] = *(const f2*)&Ws[kk][tx * 8 + 2 * jp];
#pragma unroll
      for (int i = 0; i < 8; ++i)
#pragma unroll
        for (int jp = 0; jp < 4; ++jp) acc2[i][jp] += b2[jp] * a[i];
    }
  }
  const int mb = m0 + ty * 8;
  const int t  = mb >> 5;
  const int b0 = mb & 31;
#pragma unroll
  for (int j = 0; j < 8; ++j) {
    const int n = n0 + tx * 8 + j;
    const float bj = bias[n];
    float* dst = &P[((size_t)t * GDIM + n) * BATCH + b0];
#pragma unroll
    for (int i = 0; i < 8; ++i)
      dst[i] = ((j & 1) ? acc2[i][j >> 1].y : acc2[i][j >> 1].x) + bj;
  }
}

// ---------------------------------------------------------------------------
// scan: R10 engine + dual-path sentinel exchange.
// Group g = bid&7: with round-robin block->XCD dispatch (XCD = bid%8, m09),
// all 32 blocks of a group SHARE one XCD L2. Producer writes h to BOTH:
//   hb2 (plain store -> write-through L1 into the shared L2; fast path)
//   hbL (sc0 sc1 store -> LLC; placement-independent truth)
// Consumer polls both in ONE vmcnt group (4x dwordx4) and accepts per lane
// whichever source cleared the sentinel. Co-XCD -> ~2-3x faster detection;
// wrong placement -> identical to R10's LLC path. No deadlock mode.
// Everything else verbatim R10 (padded LDS, 3 barriers, 156 VGPR).
// ---------------------------------------------------------------------------
__launch_bounds__(256, 1)
__global__ void scan_kernel(const float* __restrict__ xp,    // [TCHUNK][GDIM][BATCH]
                            const float* __restrict__ Whh,   // [GDIM][HDIM]
                            float* __restrict__ hout,        // [TCHUNK][BATCH][HDIM]
                            float* __restrict__ hb2,         // [TCHUNK+1][8][4][512] L2 path
                            float* __restrict__ hbL,         // [TCHUNK+1][8][4][512] LLC path
                            float* __restrict__ ccur,        // [BATCH][HDIM]
                            int first) {
  __shared__ float h_s[2112];       // 16 slices x 132 floats (4-float pad/slice)
  __shared__ float red[1024];       // [w][row l][chain] cross-wave partials
  __shared__ float gate_s[256];
  __shared__ float pad[17408];      // 68KB -> ~81.3KB total -> 1 block/CU

  const int tid = threadIdx.x, bid = blockIdx.x;
  const int g = bid & 7, rank = bid >> 3, slot16 = rank * 16;
  const int w = tid >> 6, l = tid & 63;
  const int s4 = l & 3, rq = l >> 2;
  const int sg = 4 * w + s4;        // this thread's 32-k slice (16 slices)
  const int cx = sg & 7;            // W column-permute key (matches LDS octet swz)
  const int kb = 32 * sg;

  // ---- W_hh slice into VGPRs, column-permuted ----
  float wreg[4][32];
#pragma unroll
  for (int r = 0; r < 4; ++r) {
    const int rl = 4 * rq + r;
    const float* wp = Whh + (size_t)((rl >> 4) * HDIM + slot16 + (rl & 15)) * HDIM + kb;
#pragma unroll
    for (int e = 0; e < 32; ++e) wreg[r][e] = wp[e ^ cx];
  }

  // staging role (t-invariant): chain cl, 8 words at global K = 128w + 8m + i
  const int cl = l >> 4, m = l & 15;
  const int sgS = 4 * w + (m >> 2);
  const int sig = sgS & 7;
  int dsaddr[8];
#pragma unroll
  for (int i = 0; i < 8; ++i)
    dsaddr[i] = 132 * sgS + 4 * (8 * (m & 3) + (i ^ sig)) + cl;
  const int srcoff = cl * 512 + 128 * w + 8 * m;

  // gate-cell role (1 pre-activation per thread): q=tid>>6, j, b
  const int qg = tid >> 6, jg = (tid >> 2) & 15, bg = tid & 3;
  const float* xq = xp + (size_t)(qg * HDIM + slot16 + jg) * BATCH + g * 4 + bg;

  // update role (wave 0): cell (slot16 + jj, chain bb)
  const int jj = l >> 2, bb = l & 3;

  float c_st = 0.f;
  if (!first && w == 0) c_st = ccur[(size_t)(g * 4 + bb) * HDIM + slot16 + jj];

  const float* hptr = &h_s[132 * sg];   // padded slice base (conflict-free reads)

#pragma unroll 1
  for (int tt = 0; tt < TCHUNK; ++tt) {
    // ---- dual-path poll + stage h(tt): data is the flag ----
    const float* s2 = hb2 + (size_t)tt * SLAB_F + g * 2048 + srcoff;
    const float* sL = hbL + (size_t)tt * SLAB_F + g * 2048 + srcoff;
    f4 va, vb;
    int guard = 0;
    while (true) {
      f4 a2, b2v, aL, bL;
      asm volatile("global_load_dwordx4 %0, %4, off sc0\n\t"
                   "global_load_dwordx4 %1, %4, off offset:16 sc0\n\t"
                   "global_load_dwordx4 %2, %5, off sc0 sc1\n\t"
                   "global_load_dwordx4 %3, %5, off offset:16 sc0 sc1\n\t"
                   "s_waitcnt vmcnt(0)"
                   : "=&v"(a2), "=&v"(b2v), "=&v"(aL), "=&v"(bL)
                   : "v"(s2), "v"(sL) : "memory");
      const bool ok2 = OK8(a2, b2v);
      const bool okL = OK8(aL, bL);
      if (__all(ok2 | okL) || ++guard > 200000) {
        va = ok2 ? a2 : aL;
        vb = ok2 ? b2v : bL;
        break;
      }
      __builtin_amdgcn_s_sleep(1);
    }
    h_s[dsaddr[0]] = va.x; h_s[dsaddr[1]] = va.y;
    h_s[dsaddr[2]] = va.z; h_s[dsaddr[3]] = va.w;
    h_s[dsaddr[4]] = vb.x; h_s[dsaddr[5]] = vb.y;
    h_s[dsaddr[6]] = vb.z; h_s[dsaddr[7]] = vb.w;
    const float xpv = xq[(size_t)tt * XPSTEP];
    BARRIER();                                  // h_s(tt) ready

    // ---- partials: 4 rows x 4 chains, linear imm-offset ds_read_b128 ----
    f2 a01[4], a23[4];
#pragma unroll
    for (int r = 0; r < 4; ++r) { a01[r] = (f2){0.f, 0.f}; a23[r] = (f2){0.f, 0.f}; }
#pragma unroll
    for (int kk = 0; kk < 32; ++kk) {
      const f4 hv = *(const f4*)&hptr[4 * kk];
      const f2 h01 = {hv.x, hv.y}, h23 = {hv.z, hv.w};
#pragma unroll
      for (int r = 0; r < 4; ++r) {
        a01[r] += h01 * wreg[r][kk];
        a23[r] += h23 * wreg[r][kk];
      }
    }
#pragma unroll
    for (int r = 0; r < 4; ++r) {
      a01[r].x = quad_sum(a01[r].x); a01[r].y = quad_sum(a01[r].y);
      a23[r].x = quad_sum(a23[r].x); a23[r].y = quad_sum(a23[r].y);
    }
    f2 r01, r23;
    { const f2 v0 = (s4 & 1) ? a01[1] : a01[0];
      const f2 v1 = (s4 & 1) ? a01[3] : a01[2];
      r01 = (s4 & 2) ? v1 : v0;
      const f2 u0 = (s4 & 1) ? a23[1] : a23[0];
      const f2 u1 = (s4 & 1) ? a23[3] : a23[2];
      r23 = (s4 & 2) ? u1 : u0; }
    *(f4*)&red[(w << 8) + 4 * l] = (f4){r01.x, r01.y, r23.x, r23.y};
    BARRIER();                                  // red(tt) ready

    // ---- cross-wave reduce + xp + activation (1 cell/thread) ----
    const float pre = red[tid] + red[256 + tid] + red[512 + tid] + red[768 + tid] + xpv;
    gate_s[tid] = (qg == 2) ? tanhf(pre) : 1.f / (1.f + __expf(-pre));
    BARRIER();                                  // gates ready

    // ---- c/h update + dual exchange store (wave 0) ----
    if (w == 0) {
      const float ig = gate_s[jj * 4 + bb];
      const float fg = gate_s[64 + jj * 4 + bb];
      const float gg = gate_s[128 + jj * 4 + bb];
      const float og = gate_s[192 + jj * 4 + bb];
      c_st = fg * c_st + ig * gg;
      const float hval = og * tanhf(c_st);
      const size_t ho = (size_t)(tt + 1) * SLAB_F + g * 2048 + bb * 512 + slot16 + jj;
      hb2[ho] = hval;                           // plain store -> shared-XCD L2
      llc_store(hbL + ho, hval);                // LLC truth copy
      hout[(size_t)tt * (BATCH * HDIM) + (size_t)(g * 4 + bb) * HDIM + slot16 + jj] = hval;
    }
  }
  if (w == 0) ccur[(size_t)(g * 4 + bb) * HDIM + slot16 + jj] = c_st;
  ((volatile float*)pad)[tid] = c_st;           // keep LDS pad allocated
}

// ---------------------------------------------------------------------------
// head: logits = h2 @ W3^T + b3 ; softmax over 10. One wave per row.
// ---------------------------------------------------------------------------
__launch_bounds__(256, 2)
__global__ void head_kernel(const float* __restrict__ h2,
                            const float* __restrict__ W3,
                            const float* __restrict__ b3,
                            float* __restrict__ outp) {
  const int tid = threadIdx.x;
  const int lane = tid & 63;
  const int wv = tid >> 6;
  const int row = blockIdx.x * 4 + wv;
  const float* hrow = &h2[(size_t)row * HDIM];
  float hreg[8];
  *(float4*)&hreg[0] = *(const float4*)&hrow[lane * 8];
  *(float4*)&hreg[4] = *(const float4*)&hrow[lane * 8 + 4];
  float logit[ODIM];
#pragma unroll
  for (int o = 0; o < ODIM; ++o) {
    const float* wrow = &W3[o * HDIM + lane * 8];
    float w[8];
    *(float4*)&w[0] = *(const float4*)&wrow[0];
    *(float4*)&w[4] = *(const float4*)&wrow[4];
    float pp = 0.f;
#pragma unroll
    for (int j = 0; j < 8; ++j) pp += hreg[j] * w[j];
#pragma unroll
    for (int off = 32; off > 0; off >>= 1) pp += __shfl_xor(pp, off);
    logit[o] = pp + b3[o];
  }
  float mx = logit[0];
#pragma unroll
  for (int o = 1; o < ODIM; ++o) mx = fmaxf(mx, logit[o]);
  float ssum = 0.f;
#pragma unroll
  for (int o = 0; o < ODIM; ++o) { logit[o] = __expf(logit[o] - mx); ssum += logit[o]; }
  const float inv = 1.f / ssum;
  if (lane == 0) {
    float* dst = &outp[(size_t)row * ODIM];
#pragma unroll
    for (int o = 0; o < ODIM; ++o) dst[o] = logit[o] * inv;
  }
}

// ---------------------------------------------------------------------------
extern "C" void kernel_launch(void* const* d_in, const int* in_sizes, int n_in,
                              void* d_out, int out_size, void* d_ws, size_t ws_size,
                              hipStream_t stream) {
  const float* data  = (const float*)d_in[0];
  const float* W_ih1 = (const float*)d_in[1];
  const float* W_hh1 = (const float*)d_in[2];
  const float* b1    = (const float*)d_in[3];
  const float* W_ih2 = (const float*)d_in[4];
  const float* W_hh2 = (const float*)d_in[5];
  const float* b2    = (const float*)d_in[6];
  const float* W3    = (const float*)d_in[7];
  const float* b3    = (const float*)d_in[8];
  float* outp = (float*)d_out;

  char* ws = (char*)d_ws;
  size_t off = 0;
  float* xp    = (float*)(ws + off); off += (size_t)TCHUNK * GDIM * BATCH * 4;     // 32MB
  float* h1c   = (float*)(ws + off); off += (size_t)TCHUNK * BATCH * HDIM * 4;     // 8MB
  float* h2c   = (float*)(ws + off); off += (size_t)TCHUNK * BATCH * HDIM * 4;     // 8MB
  float* hb2a  = (float*)(ws + off); off += (size_t)(TCHUNK + 1) * SLAB_B;         // 8.45MB
  float* hbLa  = (float*)(ws + off); off += (size_t)(TCHUNK + 1) * SLAB_B;
  float* hb2b  = (float*)(ws + off); off += (size_t)(TCHUNK + 1) * SLAB_B;
  float* hbLb  = (float*)(ws + off); off += (size_t)(TCHUNK + 1) * SLAB_B;
  float* ccur1 = (float*)(ws + off); off += BATCH * HDIM * 4;
  float* ccur2 = (float*)(ws + off); off += BATCH * HDIM * 4;
  if (off > ws_size) return;   // ws too small: bail visibly

  // slab 0 = h(0) = zeros; slabs 1..TCHUNK = sentinel 0xFFFFFFFF
  hipMemsetAsync(hb2a, 0x00, SLAB_B, stream);
  hipMemsetAsync((char*)hb2a + SLAB_B, 0xFF, (size_t)TCHUNK * SLAB_B, stream);
  hipMemsetAsync(hbLa, 0x00, SLAB_B, stream);
  hipMemsetAsync((char*)hbLa + SLAB_B, 0xFF, (size_t)TCHUNK * SLAB_B, stream);
  hipMemsetAsync(hb2b, 0x00, SLAB_B, stream);
  hipMemsetAsync((char*)hb2b + SLAB_B, 0xFF, (size_t)TCHUNK * SLAB_B, stream);
  hipMemsetAsync(hbLb, 0x00, SLAB_B, stream);
  hipMemsetAsync((char*)hbLb + SLAB_B, 0xFF, (size_t)TCHUNK * SLAB_B, stream);

  const dim3 pgrid(GDIM / 128, (TCHUNK * BATCH) / 128);

#define RECYCLE(HB) do {                                                    \
    hipMemcpyAsync(HB, (char*)HB + (size_t)TCHUNK * SLAB_B, SLAB_B,         \
                   hipMemcpyDeviceToDevice, stream);                        \
    hipMemsetAsync((char*)HB + SLAB_B, 0xFF, (size_t)TCHUNK * SLAB_B, stream); \
  } while (0)

  for (int c = 0; c < NCHUNK; ++c) {
    const float* xin = data + (size_t)c * TCHUNK * BATCH * IDIM;
    proj_kernel<IDIM><<<pgrid, 256, 0, stream>>>(xin, W_ih1, b1, xp);
    scan_kernel<<<NBLK, 256, 0, stream>>>(xp, W_hh1, h1c, hb2a, hbLa, ccur1, c == 0);
    if (c < NCHUNK - 1) { RECYCLE(hb2a); RECYCLE(hbLa); }
    proj_kernel<HDIM><<<pgrid, 256, 0, stream>>>(h1c, W_ih2, b2, xp);
    scan_kernel<<<NBLK, 256, 0, stream>>>(xp, W_hh2, h2c, hb2b, hbLb, ccur2, c == 0);
    if (c < NCHUNK - 1) { RECYCLE(hb2b); RECYCLE(hbLb); }
    head_kernel<<<(TCHUNK * BATCH) / 4, 256, 0, stream>>>(
        h2c, W3, b3, outp + (size_t)c * TCHUNK * BATCH * ODIM);
  }
#undef RECYCLE
}